// Round 1
// baseline (73.812 us; speedup 1.0000x reference)
//
#include <hip/hip_runtime.h>
#include <math.h>

#define BDIM 512
#define DDIM 512

constexpr float EPS   = 1e-6f;
constexpr float LN2   = 0.6931471805599453f;
constexpr float LOG2E = 1.4426950408889634f;

__device__ __forceinline__ float wave_reduce_sum(float v) {
  #pragma unroll
  for (int o = 32; o > 0; o >>= 1) v += __shfl_down(v, o, 64);
  return v;
}
__device__ __forceinline__ float wave_reduce_max(float v) {
  #pragma unroll
  for (int o = 32; o > 0; o >>= 1) v = fmaxf(v, __shfl_down(v, o, 64));
  return v;
}

// ---------------------------------------------------------------------------
// Kernel 1: per-row l2-normalize mu -> n; ld[r] = sum_d ln(sigma+EPS);
// mrow[r] = mean_d sigma. grid (512, 2): y=0 -> (mu1,s1), y=1 -> (mu2,s2).
// Also zero-inits pmax (ws is poisoned 0xAA by harness).
// ---------------------------------------------------------------------------
__global__ __launch_bounds__(256) void prep_kernel(
    const float* __restrict__ mu1, const float* __restrict__ s1,
    const float* __restrict__ mu2, const float* __restrict__ s2,
    float* __restrict__ nrm,        // n1 at 0, n2 at +B*D
    float* __restrict__ ld,         // ld1 at 0, ld2 at +B
    float* __restrict__ mrow,       // m1 at 0, m2 at +B
    unsigned* __restrict__ pmax_u) {
  const int r = blockIdx.x;
  const int which = blockIdx.y;
  const float* __restrict__ mu = which ? mu2 : mu1;
  const float* __restrict__ sg = which ? s2 : s1;
  float* __restrict__ nout = nrm + which * (BDIM * DDIM);
  const int t = threadIdx.x;

  const float a  = mu[r * DDIM + t];
  const float b  = mu[r * DDIM + t + 256];
  const float sa = sg[r * DDIM + t];
  const float sb = sg[r * DDIM + t + 256];

  float v0 = a * a + b * b;
  float v1 = __log2f(sa + EPS) + __log2f(sb + EPS);
  float v2 = sa + sb;

  __shared__ float red[3][4];
  __shared__ float sinv;
  const int wid = t >> 6, lane = t & 63;
  v0 = wave_reduce_sum(v0);
  v1 = wave_reduce_sum(v1);
  v2 = wave_reduce_sum(v2);
  if (lane == 0) { red[0][wid] = v0; red[1][wid] = v1; red[2][wid] = v2; }
  __syncthreads();
  if (t == 0) {
    float sq = red[0][0] + red[0][1] + red[0][2] + red[0][3];
    float lg = red[1][0] + red[1][1] + red[1][2] + red[1][3];
    float sm = red[2][0] + red[2][1] + red[2][2] + red[2][3];
    ld[which * BDIM + r]   = LN2 * lg;
    mrow[which * BDIM + r] = sm * (1.0f / DDIM);
    sinv = 1.0f / fmaxf(sqrtf(sq), 1e-12f);
    if (which == 0) pmax_u[r] = 0u;
  }
  __syncthreads();
  const float inv = sinv;
  nout[r * DDIM + t]       = a * inv;
  nout[r * DDIM + t + 256] = b * inv;
}

// ---------------------------------------------------------------------------
// Kernel 2: the B^2*D pass. 32x32 tile per block, 2x2 pairs per thread.
// Accumulates term1 = sum diff^2/(savg+EPS), sum log2(savg+EPS), dot(n1,n2).
// Epilogue: sim[i,j] = exp(-bd/D); p = exp(2*dot) (monotone surrogate of
// sim2) -> pdiag + atomicMax off-diag row max.
// ---------------------------------------------------------------------------
__global__ __launch_bounds__(256) void bd_kernel(
    const float* __restrict__ n1, const float* __restrict__ n2,
    const float* __restrict__ s1, const float* __restrict__ s2,
    const float* __restrict__ ld, float* __restrict__ sim,
    unsigned* __restrict__ pmax_u, float* __restrict__ pdiag) {
  __shared__ float An[32][65];
  __shared__ float As[32][65];
  __shared__ float Bn[32][65];
  __shared__ float Bs[32][65];

  const int i0 = blockIdx.y * 32, j0 = blockIdx.x * 32;
  const int t  = threadIdx.x;
  const int il = (t >> 4) * 2;   // 0..30, step 2
  const int jl = (t & 15) * 2;   // 0..30, step 2

  float t1[2][2]  = {{0.f, 0.f}, {0.f, 0.f}};
  float lda[2][2] = {{0.f, 0.f}, {0.f, 0.f}};
  float dac[2][2] = {{0.f, 0.f}, {0.f, 0.f}};

  for (int dc = 0; dc < DDIM; dc += 64) {
    __syncthreads();
    #pragma unroll
    for (int q = 0; q < 2; ++q) {
      const int f   = t + q * 256;   // 0..511 -> 512 float4 per array
      const int row = f >> 4;
      const int c4  = (f & 15) * 4;
      const float4 va = *(const float4*)&n1[(i0 + row) * DDIM + dc + c4];
      const float4 vs = *(const float4*)&s1[(i0 + row) * DDIM + dc + c4];
      const float4 vb = *(const float4*)&n2[(j0 + row) * DDIM + dc + c4];
      const float4 vt = *(const float4*)&s2[(j0 + row) * DDIM + dc + c4];
      An[row][c4 + 0] = va.x; An[row][c4 + 1] = va.y; An[row][c4 + 2] = va.z; An[row][c4 + 3] = va.w;
      As[row][c4 + 0] = vs.x; As[row][c4 + 1] = vs.y; As[row][c4 + 2] = vs.z; As[row][c4 + 3] = vs.w;
      Bn[row][c4 + 0] = vb.x; Bn[row][c4 + 1] = vb.y; Bn[row][c4 + 2] = vb.z; Bn[row][c4 + 3] = vb.w;
      Bs[row][c4 + 0] = vt.x; Bs[row][c4 + 1] = vt.y; Bs[row][c4 + 2] = vt.z; Bs[row][c4 + 3] = vt.w;
    }
    __syncthreads();

    #pragma unroll 4
    for (int d = 0; d < 64; ++d) {
      const float a0n = An[il][d],     a1n = An[il + 1][d];
      const float a0s = As[il][d],     a1s = As[il + 1][d];
      const float b0n = Bn[jl][d],     b1n = Bn[jl + 1][d];
      const float b0s = Bs[jl][d],     b1s = Bs[jl + 1][d];
      {
        const float sv = fmaf(0.5f, a0s + b0s, EPS);
        const float df = a0n - b0n;
        t1[0][0]  = fmaf(df * df, __builtin_amdgcn_rcpf(sv), t1[0][0]);
        lda[0][0] += __log2f(sv);
        dac[0][0] = fmaf(a0n, b0n, dac[0][0]);
      }
      {
        const float sv = fmaf(0.5f, a0s + b1s, EPS);
        const float df = a0n - b1n;
        t1[0][1]  = fmaf(df * df, __builtin_amdgcn_rcpf(sv), t1[0][1]);
        lda[0][1] += __log2f(sv);
        dac[0][1] = fmaf(a0n, b1n, dac[0][1]);
      }
      {
        const float sv = fmaf(0.5f, a1s + b0s, EPS);
        const float df = a1n - b0n;
        t1[1][0]  = fmaf(df * df, __builtin_amdgcn_rcpf(sv), t1[1][0]);
        lda[1][0] += __log2f(sv);
        dac[1][0] = fmaf(a1n, b0n, dac[1][0]);
      }
      {
        const float sv = fmaf(0.5f, a1s + b1s, EPS);
        const float df = a1n - b1n;
        t1[1][1]  = fmaf(df * df, __builtin_amdgcn_rcpf(sv), t1[1][1]);
        lda[1][1] += __log2f(sv);
        dac[1][1] = fmaf(a1n, b1n, dac[1][1]);
      }
    }
  }

  // epilogue
  const float l1v[2] = { ld[i0 + il], ld[i0 + il + 1] };
  const float l2v[2] = { ld[BDIM + j0 + jl], ld[BDIM + j0 + jl + 1] };
  float rmax[2] = {0.f, 0.f};
  #pragma unroll
  for (int ii = 0; ii < 2; ++ii) {
    #pragma unroll
    for (int jj = 0; jj < 2; ++jj) {
      const int gi = i0 + il + ii, gj = j0 + jl + jj;
      const float ldavg_ln = LN2 * lda[ii][jj];
      const float bd = fmaf(0.125f, t1[ii][jj],
                            0.5f * (ldavg_ln - 0.5f * (l1v[ii] + l2v[jj])));
      sim[gi * BDIM + gj] = exp2f(bd * (-LOG2E / (float)DDIM));
      const float p = exp2f((2.0f * LOG2E) * dac[ii][jj]);
      if (gi == gj) pdiag[gi] = p;
      else          rmax[ii]  = fmaxf(rmax[ii], p);
    }
  }
  #pragma unroll
  for (int m = 1; m < 16; m <<= 1) {
    rmax[0] = fmaxf(rmax[0], __shfl_xor(rmax[0], m, 64));
    rmax[1] = fmaxf(rmax[1], __shfl_xor(rmax[1], m, 64));
  }
  if ((t & 15) == 0) {
    atomicMax(&pmax_u[i0 + il],     __float_as_uint(rmax[0]));
    atomicMax(&pmax_u[i0 + il + 1], __float_as_uint(rmax[1]));
  }
}

// ---------------------------------------------------------------------------
// Kernel 3: per-row and per-column LSE of logits = scale*sim, plus diag.
// One block per index b (row b and column b).
// ---------------------------------------------------------------------------
__global__ __launch_bounds__(256) void lse_kernel(
    const float* __restrict__ sim, const float* __restrict__ lscale,
    float* __restrict__ lse_row, float* __restrict__ lse_col,
    float* __restrict__ dlog) {
  const int b = blockIdx.x;
  const int t = threadIdx.x;
  const float sc = *lscale;
  const float r0 = sc * sim[b * BDIM + t];
  const float r1 = sc * sim[b * BDIM + t + 256];
  const float c0 = sc * sim[t * BDIM + b];
  const float c1 = sc * sim[(t + 256) * BDIM + b];

  __shared__ float red[4];
  const int wid = t >> 6, lane = t & 63;

  float rm = wave_reduce_max(fmaxf(r0, r1));
  if (lane == 0) red[wid] = rm;
  __syncthreads();
  rm = fmaxf(fmaxf(red[0], red[1]), fmaxf(red[2], red[3]));
  __syncthreads();

  float cm = wave_reduce_max(fmaxf(c0, c1));
  if (lane == 0) red[wid] = cm;
  __syncthreads();
  cm = fmaxf(fmaxf(red[0], red[1]), fmaxf(red[2], red[3]));
  __syncthreads();

  float rs = wave_reduce_sum(exp2f((r0 - rm) * LOG2E) + exp2f((r1 - rm) * LOG2E));
  if (lane == 0) red[wid] = rs;
  __syncthreads();
  rs = red[0] + red[1] + red[2] + red[3];
  __syncthreads();

  float cs = wave_reduce_sum(exp2f((c0 - cm) * LOG2E) + exp2f((c1 - cm) * LOG2E));
  if (lane == 0) red[wid] = cs;
  __syncthreads();
  cs = red[0] + red[1] + red[2] + red[3];

  if (t == 0) {
    lse_row[b] = rm + LN2 * __log2f(rs);
    lse_col[b] = cm + LN2 * __log2f(cs);
    dlog[b]    = sc * sim[b * BDIM + b];
  }
}

// ---------------------------------------------------------------------------
// Kernel 4: final reductions -> 3 scalars.
// ---------------------------------------------------------------------------
__global__ __launch_bounds__(512) void final_kernel(
    const float* __restrict__ pdiag, const unsigned* __restrict__ pmax_u,
    const float* __restrict__ mrow, const float* __restrict__ lse_row,
    const float* __restrict__ lse_col, const float* __restrict__ dlog,
    float* __restrict__ out) {
  const int t = threadIdx.x;  // 0..511
  const float pm = __uint_as_float(pmax_u[t]);
  const float u  = exp2f(-(pdiag[t] / pm) * LOG2E);   // exp(-diag/negmax)
  const float as = 0.5f * (mrow[t] + mrow[BDIM + t]);

  float vals[6];
  vals[0] = u;
  vals[1] = u * u;
  vals[2] = as * as;
  vals[3] = u * as;
  vals[4] = lse_row[t] - dlog[t];
  vals[5] = lse_col[t] - dlog[t];

  __shared__ float red[6][8];
  const int wid = t >> 6, lane = t & 63;
  #pragma unroll
  for (int k = 0; k < 6; ++k) {
    const float v = wave_reduce_sum(vals[k]);
    if (lane == 0) red[k][wid] = v;
  }
  __syncthreads();
  if (t == 0) {
    float s[6];
    #pragma unroll
    for (int k = 0; k < 6; ++k) {
      float a = 0.f;
      #pragma unroll
      for (int w = 0; w < 8; ++w) a += red[k][w];
      s[k] = a;
    }
    const float mean_u = s[0] * (1.0f / BDIM);
    const float cosv = s[3] / fmaxf(sqrtf(s[1]) * sqrtf(s[2]), 1e-24f);
    out[0] = 0.5f * (s[4] + s[5]) * (1.0f / BDIM);  // loss_pro
    out[1] = 2.4f * (1.0f - cosv);                  // loss_rank * 2.4
    out[2] = 0.5f * mean_u;                         // var_loss
  }
}

extern "C" void kernel_launch(void* const* d_in, const int* in_sizes, int n_in,
                              void* d_out, int out_size, void* d_ws, size_t ws_size,
                              hipStream_t stream) {
  const float* mu1 = (const float*)d_in[0];
  const float* s1  = (const float*)d_in[1];
  const float* mu2 = (const float*)d_in[2];
  const float* s2  = (const float*)d_in[3];
  const float* lsc = (const float*)d_in[4];
  float* out = (float*)d_out;

  float* ws      = (float*)d_ws;
  float* n1      = ws;                       // 512*512
  float* n2      = n1 + BDIM * DDIM;         // 512*512
  float* sim     = n2 + BDIM * DDIM;         // 512*512
  float* ld      = sim + BDIM * BDIM;        // 2*512
  float* mrow    = ld + 2 * BDIM;            // 2*512
  float* pmaxf   = mrow + 2 * BDIM;          // 512
  float* pdiag   = pmaxf + BDIM;             // 512
  float* lse_row = pdiag + BDIM;             // 512
  float* lse_col = lse_row + BDIM;           // 512
  float* dlog    = lse_col + BDIM;           // 512

  prep_kernel<<<dim3(BDIM, 2), 256, 0, stream>>>(mu1, s1, mu2, s2, n1, ld, mrow,
                                                 (unsigned*)pmaxf);
  bd_kernel<<<dim3(16, 16), 256, 0, stream>>>(n1, n2, s1, s2, ld, sim,
                                              (unsigned*)pmaxf, pdiag);
  lse_kernel<<<BDIM, 256, 0, stream>>>(sim, lsc, lse_row, lse_col, dlog);
  final_kernel<<<1, 512, 0, stream>>>(pdiag, (unsigned*)pmaxf, mrow, lse_row,
                                      lse_col, dlog, out);
}

// Round 2
// 72.448 us; speedup vs baseline: 1.0188x; 1.0188x over previous
//
#include <hip/hip_runtime.h>
#include <math.h>

#define BDIM 512
#define DDIM 512

constexpr float EPS   = 1e-6f;
constexpr float HEPS  = 0.5e-6f;
constexpr float LN2   = 0.6931471805599453f;
constexpr float LOG2E = 1.4426950408889634f;

__device__ __forceinline__ float wave_reduce_sum(float v) {
  #pragma unroll
  for (int o = 32; o > 0; o >>= 1) v += __shfl_down(v, o, 64);
  return v;
}
__device__ __forceinline__ float wave_reduce_max(float v) {
  #pragma unroll
  for (int o = 32; o > 0; o >>= 1) v = fmaxf(v, __shfl_down(v, o, 64));
  return v;
}

// ---------------------------------------------------------------------------
// Kernel 1: per-row l2-normalize mu; emit interleaved pairs
// pX[r][d] = (n, 0.5*sigma + 0.5*EPS)  so that bd's sv = A.y + B.y.
// Also ld[r] = sum_d ln(sigma+EPS), mrow[r] = mean sigma, pmax init.
// ---------------------------------------------------------------------------
__global__ __launch_bounds__(256) void prep_kernel(
    const float* __restrict__ mu1, const float* __restrict__ s1,
    const float* __restrict__ mu2, const float* __restrict__ s2,
    float2* __restrict__ pA, float2* __restrict__ pB,
    float* __restrict__ ld,         // ld1 at 0, ld2 at +B
    float* __restrict__ mrow,       // m1 at 0, m2 at +B
    unsigned* __restrict__ pmax_u) {
  const int r = blockIdx.x;
  const int which = blockIdx.y;
  const float* __restrict__ mu = which ? mu2 : mu1;
  const float* __restrict__ sg = which ? s2 : s1;
  float2* __restrict__ pout = which ? pB : pA;
  const int t = threadIdx.x;

  const float a  = mu[r * DDIM + t];
  const float b  = mu[r * DDIM + t + 256];
  const float sa = sg[r * DDIM + t];
  const float sb = sg[r * DDIM + t + 256];

  float v0 = a * a + b * b;
  float v1 = __log2f(sa + EPS) + __log2f(sb + EPS);
  float v2 = sa + sb;

  __shared__ float red[3][4];
  __shared__ float sinv;
  const int wid = t >> 6, lane = t & 63;
  v0 = wave_reduce_sum(v0);
  v1 = wave_reduce_sum(v1);
  v2 = wave_reduce_sum(v2);
  if (lane == 0) { red[0][wid] = v0; red[1][wid] = v1; red[2][wid] = v2; }
  __syncthreads();
  if (t == 0) {
    float sq = red[0][0] + red[0][1] + red[0][2] + red[0][3];
    float lg = red[1][0] + red[1][1] + red[1][2] + red[1][3];
    float sm = red[2][0] + red[2][1] + red[2][2] + red[2][3];
    ld[which * BDIM + r]   = LN2 * lg;
    mrow[which * BDIM + r] = sm * (1.0f / DDIM);
    sinv = 1.0f / fmaxf(sqrtf(sq), 1e-12f);
    if (which == 0) pmax_u[r] = 0u;
  }
  __syncthreads();
  const float inv = sinv;
  pout[r * DDIM + t]       = make_float2(a * inv, fmaf(0.5f, sa, HEPS));
  pout[r * DDIM + t + 256] = make_float2(b * inv, fmaf(0.5f, sb, HEPS));
}

// ---------------------------------------------------------------------------
// Kernel 2: the B^2*D pass. 32x32 tile per block; 1024 threads = 4 wave-groups
// each owning a 128-wide D-slice (8 chunks of 16 d's). 2x2 register blocking.
// LDS: per group, A/B tiles of float2 pairs, 17-pair row stride (2-way max
// bank aliasing on ds_read_b64 = free). log2 taken over products of 4 sv's.
// Tail: groups 1-3 dump partials to LDS, group 0 combines + epilogue.
// ---------------------------------------------------------------------------
#define TROW 17                     // pairs per LDS row (16 + 1 pad)
#define GTILE (2 * 32 * TROW)       // float2 per group (A + B)

__global__ __launch_bounds__(1024) void bd_kernel(
    const float2* __restrict__ pA, const float2* __restrict__ pB,
    const float* __restrict__ ld, float* __restrict__ sim,
    unsigned* __restrict__ pmax_u, float* __restrict__ pdiag) {
  // max(tiles: 4*GTILE*8B = 34816B, combine: 3*256*13*4B = 39936B)
  __shared__ __align__(16) float smem[9984];

  const int t   = threadIdx.x;
  const int grp = t >> 8;          // 0..3 (D-slice)
  const int lt  = t & 255;         // lane in group
  const int i0 = blockIdx.y * 32, j0 = blockIdx.x * 32;
  const int il = (lt >> 4) * 2;    // 0..30 step 2
  const int jl = (lt & 15) * 2;

  float2* tA = (float2*)smem + grp * GTILE;
  float2* tB = tA + 32 * TROW;

  float t1[2][2]  = {{0.f,0.f},{0.f,0.f}};
  float lda[2][2] = {{0.f,0.f},{0.f,0.f}};
  float dac[2][2] = {{0.f,0.f},{0.f,0.f}};

  const float2* a0p = tA + il * TROW;
  const float2* a1p = tA + (il + 1) * TROW;
  const float2* b0p = tB + jl * TROW;
  const float2* b1p = tB + (jl + 1) * TROW;

  const int dbase = grp * 128;
  for (int c = 0; c < 8; ++c) {
    const int d0 = dbase + c * 16;
    // stage this group's 16-d chunk: 2 arrays x 32 rows x 8 float4 = 512
    // float4 loads; 256 threads -> 2 each (one from A, one from B).
    {
      int f = lt;
      #pragma unroll
      for (int q = 0; q < 2; ++q, f += 256) {
        const int arr = f >> 8;          // 0 -> A, 1 -> B
        const int row = (f >> 3) & 31;
        const int dq  = (f & 7) * 2;     // even pair index in chunk
        const float2* __restrict__ src = arr ? pB : pA;
        const int grow = (arr ? j0 : i0) + row;
        const float4 v = *(const float4*)&src[grow * DDIM + d0 + dq];
        float2* dst = (arr ? tB : tA) + row * TROW + dq;
        dst[0] = make_float2(v.x, v.y);
        dst[1] = make_float2(v.z, v.w);
      }
    }
    __syncthreads();
    #pragma unroll
    for (int g4 = 0; g4 < 4; ++g4) {
      float m[2][2] = {{1.f,1.f},{1.f,1.f}};
      #pragma unroll
      for (int k = 0; k < 4; ++k) {
        const int d = g4 * 4 + k;
        const float2 A0 = a0p[d], A1 = a1p[d];
        const float2 B0 = b0p[d], B1 = b1p[d];
        #define UPD(ii, jj, Av, Bv)                                          \
          {                                                                  \
            const float sv = Av.y + Bv.y;                                    \
            const float df = Av.x - Bv.x;                                    \
            t1[ii][jj] = fmaf(df * df, __builtin_amdgcn_rcpf(sv), t1[ii][jj]);\
            m[ii][jj] *= sv;                                                 \
            dac[ii][jj] = fmaf(Av.x, Bv.x, dac[ii][jj]);                     \
          }
        UPD(0, 0, A0, B0) UPD(0, 1, A0, B1)
        UPD(1, 0, A1, B0) UPD(1, 1, A1, B1)
        #undef UPD
      }
      lda[0][0] += __log2f(m[0][0]);
      lda[0][1] += __log2f(m[0][1]);
      lda[1][0] += __log2f(m[1][0]);
      lda[1][1] += __log2f(m[1][1]);
    }
    __syncthreads();
  }

  // cross-group combine: groups 1..3 write 12 partials, group 0 reduces.
  if (grp > 0) {
    float* p = smem + ((grp - 1) * 256 + lt) * 13;
    p[0] = t1[0][0];  p[1] = t1[0][1];  p[2]  = t1[1][0];  p[3]  = t1[1][1];
    p[4] = lda[0][0]; p[5] = lda[0][1]; p[6]  = lda[1][0]; p[7]  = lda[1][1];
    p[8] = dac[0][0]; p[9] = dac[0][1]; p[10] = dac[1][0]; p[11] = dac[1][1];
  }
  __syncthreads();
  if (grp == 0) {
    #pragma unroll
    for (int g = 0; g < 3; ++g) {
      const float* p = smem + (g * 256 + lt) * 13;
      t1[0][0]  += p[0]; t1[0][1]  += p[1]; t1[1][0]  += p[2];  t1[1][1]  += p[3];
      lda[0][0] += p[4]; lda[0][1] += p[5]; lda[1][0] += p[6];  lda[1][1] += p[7];
      dac[0][0] += p[8]; dac[0][1] += p[9]; dac[1][0] += p[10]; dac[1][1] += p[11];
    }
    const float l1v[2] = { ld[i0 + il], ld[i0 + il + 1] };
    const float l2v[2] = { ld[BDIM + j0 + jl], ld[BDIM + j0 + jl + 1] };
    float rmax[2] = {0.f, 0.f};
    #pragma unroll
    for (int ii = 0; ii < 2; ++ii) {
      #pragma unroll
      for (int jj = 0; jj < 2; ++jj) {
        const int gi = i0 + il + ii, gj = j0 + jl + jj;
        const float ldavg_ln = LN2 * lda[ii][jj];
        const float bd = fmaf(0.125f, t1[ii][jj],
                              0.5f * (ldavg_ln - 0.5f * (l1v[ii] + l2v[jj])));
        sim[gi * BDIM + gj] = exp2f(bd * (-LOG2E / (float)DDIM));
        const float p = exp2f((2.0f * LOG2E) * dac[ii][jj]);
        if (gi == gj) pdiag[gi] = p;
        else          rmax[ii]  = fmaxf(rmax[ii], p);
      }
    }
    #pragma unroll
    for (int m2 = 1; m2 < 16; m2 <<= 1) {
      rmax[0] = fmaxf(rmax[0], __shfl_xor(rmax[0], m2, 64));
      rmax[1] = fmaxf(rmax[1], __shfl_xor(rmax[1], m2, 64));
    }
    if ((lt & 15) == 0) {
      atomicMax(&pmax_u[i0 + il],     __float_as_uint(rmax[0]));
      atomicMax(&pmax_u[i0 + il + 1], __float_as_uint(rmax[1]));
    }
  }
}

// ---------------------------------------------------------------------------
// Kernel 3: per-row and per-column LSE of logits = scale*sim, plus diag.
// ---------------------------------------------------------------------------
__global__ __launch_bounds__(256) void lse_kernel(
    const float* __restrict__ sim, const float* __restrict__ lscale,
    float* __restrict__ lse_row, float* __restrict__ lse_col,
    float* __restrict__ dlog) {
  const int b = blockIdx.x;
  const int t = threadIdx.x;
  const float sc = *lscale;
  const float r0 = sc * sim[b * BDIM + t];
  const float r1 = sc * sim[b * BDIM + t + 256];
  const float c0 = sc * sim[t * BDIM + b];
  const float c1 = sc * sim[(t + 256) * BDIM + b];

  __shared__ float red[4];
  const int wid = t >> 6, lane = t & 63;

  float rm = wave_reduce_max(fmaxf(r0, r1));
  if (lane == 0) red[wid] = rm;
  __syncthreads();
  rm = fmaxf(fmaxf(red[0], red[1]), fmaxf(red[2], red[3]));
  __syncthreads();

  float cm = wave_reduce_max(fmaxf(c0, c1));
  if (lane == 0) red[wid] = cm;
  __syncthreads();
  cm = fmaxf(fmaxf(red[0], red[1]), fmaxf(red[2], red[3]));
  __syncthreads();

  float rs = wave_reduce_sum(exp2f((r0 - rm) * LOG2E) + exp2f((r1 - rm) * LOG2E));
  if (lane == 0) red[wid] = rs;
  __syncthreads();
  rs = red[0] + red[1] + red[2] + red[3];
  __syncthreads();

  float cs = wave_reduce_sum(exp2f((c0 - cm) * LOG2E) + exp2f((c1 - cm) * LOG2E));
  if (lane == 0) red[wid] = cs;
  __syncthreads();
  cs = red[0] + red[1] + red[2] + red[3];

  if (t == 0) {
    lse_row[b] = rm + LN2 * __log2f(rs);
    lse_col[b] = cm + LN2 * __log2f(cs);
    dlog[b]    = sc * sim[b * BDIM + b];
  }
}

// ---------------------------------------------------------------------------
// Kernel 4: final reductions -> 3 scalars.
// ---------------------------------------------------------------------------
__global__ __launch_bounds__(512) void final_kernel(
    const float* __restrict__ pdiag, const unsigned* __restrict__ pmax_u,
    const float* __restrict__ mrow, const float* __restrict__ lse_row,
    const float* __restrict__ lse_col, const float* __restrict__ dlog,
    float* __restrict__ out) {
  const int t = threadIdx.x;  // 0..511
  const float pm = __uint_as_float(pmax_u[t]);
  const float u  = exp2f(-(pdiag[t] / pm) * LOG2E);   // exp(-diag/negmax)
  const float as = 0.5f * (mrow[t] + mrow[BDIM + t]);

  float vals[6];
  vals[0] = u;
  vals[1] = u * u;
  vals[2] = as * as;
  vals[3] = u * as;
  vals[4] = lse_row[t] - dlog[t];
  vals[5] = lse_col[t] - dlog[t];

  __shared__ float red[6][8];
  const int wid = t >> 6, lane = t & 63;
  #pragma unroll
  for (int k = 0; k < 6; ++k) {
    const float v = wave_reduce_sum(vals[k]);
    if (lane == 0) red[k][wid] = v;
  }
  __syncthreads();
  if (t == 0) {
    float s[6];
    #pragma unroll
    for (int k = 0; k < 6; ++k) {
      float a = 0.f;
      #pragma unroll
      for (int w = 0; w < 8; ++w) a += red[k][w];
      s[k] = a;
    }
    const float mean_u = s[0] * (1.0f / BDIM);
    const float cosv = s[3] / fmaxf(sqrtf(s[1]) * sqrtf(s[2]), 1e-24f);
    out[0] = 0.5f * (s[4] + s[5]) * (1.0f / BDIM);  // loss_pro
    out[1] = 2.4f * (1.0f - cosv);                  // loss_rank * 2.4
    out[2] = 0.5f * mean_u;                         // var_loss
  }
}

extern "C" void kernel_launch(void* const* d_in, const int* in_sizes, int n_in,
                              void* d_out, int out_size, void* d_ws, size_t ws_size,
                              hipStream_t stream) {
  const float* mu1 = (const float*)d_in[0];
  const float* s1  = (const float*)d_in[1];
  const float* mu2 = (const float*)d_in[2];
  const float* s2  = (const float*)d_in[3];
  const float* lsc = (const float*)d_in[4];
  float* out = (float*)d_out;

  float* ws      = (float*)d_ws;
  float2* pA     = (float2*)ws;                       // 512*512 float2 (2MB)
  float2* pB     = pA + BDIM * DDIM;                  // 2MB
  float* sim     = (float*)(pB + BDIM * DDIM);        // 1MB
  float* ld      = sim + BDIM * BDIM;                 // 2*512
  float* mrow    = ld + 2 * BDIM;                     // 2*512
  float* pmaxf   = mrow + 2 * BDIM;                   // 512
  float* pdiag   = pmaxf + BDIM;                      // 512
  float* lse_row = pdiag + BDIM;                      // 512
  float* lse_col = lse_row + BDIM;                    // 512
  float* dlog    = lse_col + BDIM;                    // 512

  prep_kernel<<<dim3(BDIM, 2), 256, 0, stream>>>(mu1, s1, mu2, s2, pA, pB, ld,
                                                 mrow, (unsigned*)pmaxf);
  bd_kernel<<<dim3(16, 16), 1024, 0, stream>>>(pA, pB, ld, sim,
                                               (unsigned*)pmaxf, pdiag);
  lse_kernel<<<BDIM, 256, 0, stream>>>(sim, lsc, lse_row, lse_col, dlog);
  final_kernel<<<1, 512, 0, stream>>>(pdiag, (unsigned*)pmaxf, mrow, lse_row,
                                      lse_col, dlog, out);
}